// Round 6
// baseline (249.363 us; speedup 1.0000x reference)
//
#include <hip/hip_runtime.h>
#include <math.h>

typedef _Float16 half_t;
typedef _Float16 half8 __attribute__((ext_vector_type(8)));
typedef _Float16 half4_t __attribute__((ext_vector_type(4)));
typedef _Float16 half2_t __attribute__((ext_vector_type(2)));
typedef float floatx4 __attribute__((ext_vector_type(4)));

#define M_TOK 512
#define N_DIM 2048
#define D_HEAD 128
#define H_HEADS 16
#define L_CACHE 4096
#define THREE_N 6144
#define NCHUNK 16
#define LCHUNK 256

// ---------------------------------------------------------------------------
// Kernel 1: merged prep. Regions by blockIdx.x:
//   [0,8192)        convert cache_K fp32 -> K16 fp16 (same [H,L,D] layout)
//   [8192,9216)     convert X fp32 -> X16 fp16
//   [9216,17408)    transpose cache_V [H,L,D] fp32 -> V16T [H,D,L] fp16
//   [17408,29696)   transpose W [K,N3] fp32 -> W16T [N3,K] fp16
// ---------------------------------------------------------------------------
__global__ __launch_bounds__(256) void prep_kernel(const float* __restrict__ cK,
                                                   const float* __restrict__ cV,
                                                   const float* __restrict__ W,
                                                   const float* __restrict__ X,
                                                   half_t* __restrict__ K16,
                                                   half_t* __restrict__ V16T,
                                                   half_t* __restrict__ W16T,
                                                   half_t* __restrict__ X16) {
    __shared__ half_t tile[32 * 36];
    int b = blockIdx.x;
    int t = threadIdx.x;

    if (b < 8192) {  // convert K
        size_t i = ((size_t)b * 256 + t) * 4;
        float4 v = *(const float4*)(cK + i);
        half4_t h = {(half_t)v.x, (half_t)v.y, (half_t)v.z, (half_t)v.w};
        *(half4_t*)(K16 + i) = h;
        return;
    }
    b -= 8192;
    if (b < 1024) {  // convert X
        size_t i = ((size_t)b * 256 + t) * 4;
        float4 v = *(const float4*)(X + i);
        half4_t h = {(half_t)v.x, (half_t)v.y, (half_t)v.z, (half_t)v.w};
        *(half4_t*)(X16 + i) = h;
        return;
    }
    b -= 1024;
    if (b < 8192) {  // transpose V: 32(l) x 32(d) tiles
        int h = b >> 9;
        int rem = b & 511;
        int lt = rem >> 2, dt = rem & 3;
        int l0 = lt * 32, d0 = dt * 32;
        {
            int li = t >> 3, c4 = (t & 7) * 4;
            float4 v = *(const float4*)(cV + ((size_t)h * L_CACHE + l0 + li) * D_HEAD + d0 + c4);
            tile[li * 36 + c4 + 0] = (half_t)v.x;
            tile[li * 36 + c4 + 1] = (half_t)v.y;
            tile[li * 36 + c4 + 2] = (half_t)v.z;
            tile[li * 36 + c4 + 3] = (half_t)v.w;
        }
        __syncthreads();
        {
            int di = t >> 3, lj = (t & 7) * 4;
            half4_t o = {tile[(lj + 0) * 36 + di], tile[(lj + 1) * 36 + di],
                         tile[(lj + 2) * 36 + di], tile[(lj + 3) * 36 + di]};
            *(half4_t*)(V16T + ((size_t)h * D_HEAD + d0 + di) * L_CACHE + l0 + lj) = o;
        }
        return;
    }
    b -= 8192;
    {  // transpose W: 32(k) x 32(n) tiles, b in [0,12288)
        int n0 = (b % 192) * 32, k0 = (b / 192) * 32;
        {
            int ki = t >> 3, n4 = (t & 7) * 4;
            float4 v = *(const float4*)(W + (size_t)(k0 + ki) * THREE_N + n0 + n4);
            tile[ki * 36 + n4 + 0] = (half_t)v.x;
            tile[ki * 36 + n4 + 1] = (half_t)v.y;
            tile[ki * 36 + n4 + 2] = (half_t)v.z;
            tile[ki * 36 + n4 + 3] = (half_t)v.w;
        }
        __syncthreads();
        {
            int ni = t >> 3, k4 = (t & 7) * 4;
            half4_t o = {tile[(k4 + 0) * 36 + ni], tile[(k4 + 1) * 36 + ni],
                         tile[(k4 + 2) * 36 + ni], tile[(k4 + 3) * 36 + ni]};
            *(half4_t*)(W16T + (size_t)(n0 + ni) * N_DIM + k0 + k4) = o;
        }
    }
}

// ---------------------------------------------------------------------------
// Kernel 2: fused GEMM + RMS-norm + scatter (incl. direct V^T write).
// Tile = X16[64m x 2048] @ W16T[128n x 2048]^T. bx 0..15 q-head, 16..31
// k-head (-> K16 rows P..P+M), 32..47 v-head (-> V16T via LDS transpose).
// Vt transpose buffer aliases As/Bs (barrier-protected) -> LDS ~28 KB.
// ---------------------------------------------------------------------------
__global__ __launch_bounds__(256) void gemm_fused_kernel(const half_t* __restrict__ X16,
                                                         const half_t* __restrict__ W16T,
                                                         const int* __restrict__ Pp,
                                                         half_t* __restrict__ Q16,
                                                         half_t* __restrict__ K16,
                                                         half_t* __restrict__ V16T) {
    __shared__ half_t smem[64 * 72 + 128 * 72];  // As | Bs ; Vt aliases front
    __shared__ float ssbuf[4][32];
    half_t* As = smem;             // [m][k] BK=64, pad 72
    half_t* Bs = smem + 64 * 72;   // [n][k]
    half_t* Vt = smem;             // [d][m] 128x72, epilogue only (after barrier)
    const int t = threadIdx.x;
    const int wid = t >> 6, lane = t & 63;
    const int quad = lane >> 4, ln = lane & 15;
    const int bx = blockIdx.x, by = blockIdx.y;
    const int m0 = by * 64, n0 = bx * 128;
    const int wm = (wid >> 1) * 32, wn = (wid & 1) * 64;

    floatx4 acc[2][4] = {};

    const int ar = t >> 3, ag = (t & 7) * 8;  // A: 32 rows/pass, 2 passes
    const int br = t >> 3, bg = (t & 7) * 8;  // B: 32 rows/pass, 4 passes

    for (int k0 = 0; k0 < N_DIM; k0 += 64) {
        __syncthreads();
#pragma unroll
        for (int p = 0; p < 2; ++p) {
            int r = ar + p * 32;
            *(half8*)&As[r * 72 + ag] =
                *(const half8*)(X16 + (size_t)(m0 + r) * N_DIM + k0 + ag);
        }
#pragma unroll
        for (int p = 0; p < 4; ++p) {
            int r = br + p * 32;
            *(half8*)&Bs[r * 72 + bg] =
                *(const half8*)(W16T + (size_t)(n0 + r) * N_DIM + k0 + bg);
        }
        __syncthreads();
#pragma unroll
        for (int kt = 0; kt < 2; ++kt) {
            half8 a[2], b[4];
#pragma unroll
            for (int i = 0; i < 2; ++i)
                a[i] = *(half8*)&As[(wm + i * 16 + ln) * 72 + kt * 32 + quad * 8];
#pragma unroll
            for (int j = 0; j < 4; ++j)
                b[j] = *(half8*)&Bs[(wn + j * 16 + ln) * 72 + kt * 32 + quad * 8];
#pragma unroll
            for (int i = 0; i < 2; ++i)
#pragma unroll
                for (int j = 0; j < 4; ++j)
                    acc[i][j] = __builtin_amdgcn_mfma_f32_16x16x32_f16(a[i], b[j], acc[i][j], 0, 0, 0);
        }
    }

    const int seg = bx >> 4, h = bx & 15;
    const int P = *Pp;

    if (seg < 2) {  // q or k: RMS-norm then write (block-uniform branch)
        float ss[2][4], scale[2][4];
#pragma unroll
        for (int i = 0; i < 2; ++i)
#pragma unroll
            for (int r = 0; r < 4; ++r) {
                float s = 0.f;
#pragma unroll
                for (int j = 0; j < 4; ++j) s += acc[i][j][r] * acc[i][j][r];
#pragma unroll
                for (int msk = 1; msk < 16; msk <<= 1) s += __shfl_xor(s, msk, 64);
                ss[i][r] = s;
            }
        if (ln == 0) {
#pragma unroll
            for (int i = 0; i < 2; ++i)
#pragma unroll
                for (int r = 0; r < 4; ++r)
                    ssbuf[wid][i * 16 + quad * 4 + r] = ss[i][r];
        }
        __syncthreads();
#pragma unroll
        for (int i = 0; i < 2; ++i)
#pragma unroll
            for (int r = 0; r < 4; ++r)
                scale[i][r] =
                    rsqrtf((ss[i][r] + ssbuf[wid ^ 1][i * 16 + quad * 4 + r]) * (1.0f / 128.0f));
#pragma unroll
        for (int i = 0; i < 2; ++i) {
            int mbase = m0 + wm + i * 16 + quad * 4;
#pragma unroll
            for (int j = 0; j < 4; ++j) {
                int col = wn + j * 16 + ln;
#pragma unroll
                for (int r = 0; r < 4; ++r) {
                    int m = mbase + r;
                    half_t val = (half_t)(acc[i][j][r] * scale[i][r]);
                    if (seg == 0)
                        Q16[((size_t)h * M_TOK + m) * D_HEAD + col] = val;
                    else
                        K16[((size_t)h * L_CACHE + P + m) * D_HEAD + col] = val;
                }
            }
        }
    } else {  // v: transpose via LDS (aliases As/Bs -> barrier first), write V^T
        __syncthreads();
#pragma unroll
        for (int i = 0; i < 2; ++i) {
            int mbase = wm + i * 16 + quad * 4;
#pragma unroll
            for (int j = 0; j < 4; ++j) {
                int d = wn + j * 16 + ln;
#pragma unroll
                for (int r = 0; r < 4; ++r)
                    Vt[d * 72 + mbase + r] = (half_t)acc[i][j][r];
            }
        }
        __syncthreads();
#pragma unroll
        for (int p = 0; p < 4; ++p) {
            int s = p * 256 + t;
            int d = s >> 3, sg = s & 7;
            *(half8*)(V16T + ((size_t)h * D_HEAD + d) * L_CACHE + P + m0 + sg * 8) =
                *(half8*)&Vt[d * 72 + sg * 8];
        }
    }
}

// ---------------------------------------------------------------------------
// Kernel 3: flash attention partial over L-chunk of 256.
// grid (x=c 16, y=h 16, z=mb 4): flat-ID stride of z is 256 (== 0 mod 8), so
// the 4 m-blocks sharing one (h,c) K/V tile land on the SAME XCD -> L2 reuse.
// 128 m-rows per block: 4 waves x 2 strips of 16 rows. Online softmax,
// unnormalized fp16 partial O + (m,l) stats in [h][m][c] layout.
// ---------------------------------------------------------------------------
__global__ __launch_bounds__(256) void attn_partial_kernel(const half_t* __restrict__ Q16,
                                                           const half_t* __restrict__ K16,
                                                           const half_t* __restrict__ V16T,
                                                           half_t* __restrict__ Opart,
                                                           float* __restrict__ mstat,
                                                           float* __restrict__ lstat) {
    __shared__ half_t Ks[64 * 136];
    __shared__ half_t Vs[128 * 72];
    __shared__ half_t Ps[4 * 16 * 72];
    const int t = threadIdx.x, w = t >> 6, lane = t & 63;
    const int quad = lane >> 4, ln = lane & 15;
    const int c = blockIdx.x, h = blockIdx.y;
    const int mb = blockIdx.z * 128;
    const half_t* Qh = Q16 + (size_t)h * M_TOK * D_HEAD;
    const half_t* Kh = K16 + (size_t)h * L_CACHE * D_HEAD;
    const half_t* Vh = V16T + (size_t)h * D_HEAD * L_CACHE;

    half8 qf[2][4];
#pragma unroll
    for (int s = 0; s < 2; ++s) {
        int m0 = mb + s * 64 + w * 16;
#pragma unroll
        for (int dt = 0; dt < 4; ++dt)
            qf[s][dt] = *(const half8*)(Qh + (size_t)(m0 + ln) * D_HEAD + dt * 32 + quad * 8);
    }

    floatx4 oacc[2][8] = {};
    float mrow[2][4], lrow[2][4];
#pragma unroll
    for (int s = 0; s < 2; ++s)
#pragma unroll
        for (int r = 0; r < 4; ++r) { mrow[s][r] = -INFINITY; lrow[s][r] = 0.f; }

    half_t* Pw = Ps + w * (16 * 72);

    for (int l0 = c * LCHUNK; l0 < (c + 1) * LCHUNK; l0 += 64) {
        __syncthreads();
        {
            int lr = t >> 4, ch = t & 15;
#pragma unroll
            for (int p = 0; p < 4; ++p, lr += 16)
                *(half8*)&Ks[lr * 136 + ch * 8] =
                    *(const half8*)(Kh + (size_t)(l0 + lr) * D_HEAD + ch * 8);
        }
        {
            int dr = t >> 3, ch = t & 7;
#pragma unroll
            for (int p = 0; p < 4; ++p, dr += 32)
                *(half8*)&Vs[dr * 72 + ch * 8] =
                    *(const half8*)(Vh + (size_t)dr * L_CACHE + l0 + ch * 8);
        }
        __syncthreads();

#pragma unroll
        for (int s = 0; s < 2; ++s) {
            floatx4 sacc[4] = {};
#pragma unroll
            for (int nt = 0; nt < 4; ++nt)
#pragma unroll
                for (int dt = 0; dt < 4; ++dt) {
                    half8 b = *(half8*)&Ks[(nt * 16 + ln) * 136 + dt * 32 + quad * 8];
                    sacc[nt] = __builtin_amdgcn_mfma_f32_16x16x32_f16(qf[s][dt], b, sacc[nt], 0, 0, 0);
                }

            float alpha[4];
#pragma unroll
            for (int r = 0; r < 4; ++r) {
                float mx = fmaxf(fmaxf(sacc[0][r], sacc[1][r]), fmaxf(sacc[2][r], sacc[3][r]));
#pragma unroll
                for (int msk = 8; msk; msk >>= 1) mx = fmaxf(mx, __shfl_xor(mx, msk, 16));
                float mnew = fmaxf(mrow[s][r], mx);
                alpha[r] = __expf(mrow[s][r] - mnew);
                mrow[s][r] = mnew;
                float psum = 0.f;
#pragma unroll
                for (int nt = 0; nt < 4; ++nt) {
                    float p = __expf(sacc[nt][r] - mnew);
                    sacc[nt][r] = p;
                    psum += p;
                }
#pragma unroll
                for (int msk = 8; msk; msk >>= 1) psum += __shfl_xor(psum, msk, 16);
                lrow[s][r] = lrow[s][r] * alpha[r] + psum;
            }

#pragma unroll
            for (int nt = 0; nt < 4; ++nt)
#pragma unroll
                for (int r = 0; r < 4; ++r)
                    Pw[(quad * 4 + r) * 72 + nt * 16 + ln] = (half_t)sacc[nt][r];

#pragma unroll
            for (int nt8 = 0; nt8 < 8; ++nt8)
#pragma unroll
                for (int r = 0; r < 4; ++r)
                    oacc[s][nt8][r] *= alpha[r];

#pragma unroll
            for (int kt = 0; kt < 2; ++kt) {
                half8 a = *(half8*)&Pw[ln * 72 + kt * 32 + quad * 8];
#pragma unroll
                for (int nt8 = 0; nt8 < 8; ++nt8) {
                    half8 b = *(half8*)&Vs[(nt8 * 16 + ln) * 72 + kt * 32 + quad * 8];
                    oacc[s][nt8] = __builtin_amdgcn_mfma_f32_16x16x32_f16(a, b, oacc[s][nt8], 0, 0, 0);
                }
            }
        }
    }

    // Opart layout [h][m][c][d]; stats [h][m][c]
#pragma unroll
    for (int s = 0; s < 2; ++s) {
        int m0 = mb + s * 64 + w * 16;
#pragma unroll
        for (int nt8 = 0; nt8 < 8; ++nt8) {
            int col = nt8 * 16 + ln;
#pragma unroll
            for (int r = 0; r < 4; ++r) {
                int m = m0 + quad * 4 + r;
                Opart[(((size_t)h * M_TOK + m) * NCHUNK + c) * D_HEAD + col] =
                    (half_t)oacc[s][nt8][r];
            }
        }
        if (ln == 0) {
#pragma unroll
            for (int r = 0; r < 4; ++r) {
                int m = m0 + quad * 4 + r;
                mstat[((size_t)h * M_TOK + m) * NCHUNK + c] = mrow[s][r];
                lstat[((size_t)h * M_TOK + m) * NCHUNK + c] = lrow[s][r];
            }
        }
    }
}

// ---------------------------------------------------------------------------
// Kernel 4: combine NCHUNK fp16 partials. One wave per (h,m) row; per-row data
// is fully contiguous (16 chunks x 128 d = 4 KB + 64 B stats).
// ---------------------------------------------------------------------------
__global__ __launch_bounds__(256) void combine_kernel(const half_t* __restrict__ Opart,
                                                      const float* __restrict__ mstat,
                                                      const float* __restrict__ lstat,
                                                      float* __restrict__ out) {
    int gw = blockIdx.x * 4 + (threadIdx.x >> 6);
    int lane = threadIdx.x & 63;
    int h = gw >> 9, m = gw & 511;
    int d = lane * 2;

    const float* msp = mstat + (size_t)gw * NCHUNK;  // gw == h*512+m
    const float* lsp = lstat + (size_t)gw * NCHUNK;
    const half_t* Ob = Opart + (size_t)gw * NCHUNK * D_HEAD;

    float ms[NCHUNK];
    float mg = -INFINITY;
#pragma unroll
    for (int c = 0; c < NCHUNK; ++c) {
        ms[c] = msp[c];
        mg = fmaxf(mg, ms[c]);
    }
    float denom = 0.f, o0 = 0.f, o1 = 0.f;
#pragma unroll
    for (int c = 0; c < NCHUNK; ++c) {
        float e = __expf(ms[c] - mg);
        denom += lsp[c] * e;
        half2_t v = *(const half2_t*)(Ob + c * D_HEAD + d);
        o0 += (float)v.x * e;
        o1 += (float)v.y * e;
    }
    float inv = 1.0f / denom;
    float* op = out + (size_t)m * N_DIM + h * D_HEAD + d;
    op[0] = o0 * inv;
    op[1] = o1 * inv;
}

// ---------------------------------------------------------------------------
extern "C" void kernel_launch(void* const* d_in, const int* in_sizes, int n_in,
                              void* d_out, int out_size, void* d_ws, size_t ws_size,
                              hipStream_t stream) {
    const float* X = (const float*)d_in[0];
    const float* W = (const float*)d_in[1];
    const float* cK = (const float*)d_in[2];
    const float* cV = (const float*)d_in[3];
    const int* Pp = (const int*)d_in[4];
    float* out = (float*)d_out;

    char* ws = (char*)d_ws;
    // workspace layout (bytes):
    //   Q16    @ 0           (2,097,152)
    //   K16    @ 2,097,152   (16,777,216)
    //   V16T   @ 18,874,368  (16,777,216)
    //   X16    @ 35,651,584  (2,097,152)
    //   W16T   @ 37,748,736  (25,165,824)  [dead after gemm_fused]
    //   Opart16@ 37,748,736  (33,554,432)  [overlays W16T]
    //   mstat  @ 71,303,168  (524,288)
    //   lstat  @ 71,827,456  (524,288)
    //   total 72,351,744
    half_t* Q16 = (half_t*)(ws + 0);
    half_t* K16 = (half_t*)(ws + 2097152);
    half_t* V16T = (half_t*)(ws + 18874368);
    half_t* X16 = (half_t*)(ws + 35651584);
    half_t* W16T = (half_t*)(ws + 37748736);
    half_t* Opart = (half_t*)(ws + 37748736);
    float* mstat = (float*)(ws + 71303168);
    float* lstat = (float*)(ws + 71827456);

    prep_kernel<<<29696, 256, 0, stream>>>(cK, cV, W, X, K16, V16T, W16T, X16);
    gemm_fused_kernel<<<dim3(48, 8), 256, 0, stream>>>(X16, W16T, Pp, Q16, K16, V16T);
    attn_partial_kernel<<<dim3(16, 16, 4), 256, 0, stream>>>(Q16, K16, V16T, Opart, mstat, lstat);
    combine_kernel<<<2048, 256, 0, stream>>>(Opart, mstat, lstat, out);
}